// Round 1
// baseline (3496.113 us; speedup 1.0000x reference)
//
#include <hip/hip_runtime.h>
#include <stdint.h>

// Problem constants (fixed by reference)
#define BATCH 2
#define TLEN  2048
#define DEMB  2048
#define NHQ   16
#define NHKV  4
#define GRP   4
#define DKV   128
#define NQKV  3072                       // 2048 q + 512 k + 512 v columns
#define ATTN_OUT_ELEMS (BATCH*TLEN*DEMB) // 8388608
// d_out layout: [attn_output (8388608) | kv_cache (B,T,4,256) (4194304)]

// ---------------------------------------------------------------------------
// threefry2x32-20, key = (0,1)  (jax.random.key(1))
// "partitionable" random-bits mode (modern JAX default): per-element uint64
// counter i -> threefry(key, (hi=0, lo=i)), 32-bit output = x0 ^ x1.
// uniform = bitcast((bits>>9)|0x3f800000) - 1;  keep = uniform < 0.9f
// ---------------------------------------------------------------------------
__device__ __forceinline__ void tf_round(uint32_t& x0, uint32_t& x1, int r) {
  x0 += x1;
  x1 = (x1 << r) | (x1 >> (32 - r));
  x1 ^= x0;
}

__device__ __forceinline__ uint32_t threefry_bits(uint32_t ctr) {
  const uint32_t ks1 = 1u, ks2 = 0x1BD11BDBu;   // ks0=0, ks2 = 0^1^0x1BD11BDA
  uint32_t x0 = 0u;            // hi counter + ks0
  uint32_t x1 = ctr + ks1;     // lo counter + ks1
  tf_round(x0,x1,13); tf_round(x0,x1,15); tf_round(x0,x1,26); tf_round(x0,x1,6);
  x0 += ks1; x1 += ks2 + 1u;
  tf_round(x0,x1,17); tf_round(x0,x1,29); tf_round(x0,x1,16); tf_round(x0,x1,24);
  x0 += ks2; x1 += 0u + 2u;
  tf_round(x0,x1,13); tf_round(x0,x1,15); tf_round(x0,x1,26); tf_round(x0,x1,6);
  x0 += 0u;  x1 += ks1 + 3u;
  tf_round(x0,x1,17); tf_round(x0,x1,29); tf_round(x0,x1,16); tf_round(x0,x1,24);
  x0 += ks1; x1 += ks2 + 4u;
  tf_round(x0,x1,13); tf_round(x0,x1,15); tf_round(x0,x1,26); tf_round(x0,x1,6);
  x0 += ks2; x1 += 0u + 5u;
  return x0 ^ x1;
}

// ---------------------------------------------------------------------------
// fp32 SGEMM body: C[m0:+128, ccol0+n0:+128] = A[M,K] @ W[K,Nw]
// 128x128 tile, BK=8, 256 threads, 8x8 per thread.
// ---------------------------------------------------------------------------
__device__ __forceinline__ void sgemm_body(const float* __restrict__ A,
                                           const float* __restrict__ W,
                                           float* __restrict__ C,
                                           int K, int Nw, int ldc, int ccol0,
                                           int m0, int n0) {
  __shared__ float As[8][132];   // [k][m], +4 pad
  __shared__ float Bs[8][132];   // [k][n]
  const int tid = threadIdx.x;
  const int tm = tid & 15, tn = tid >> 4;
  const int ar = tid >> 1, ak = (tid & 1) * 4;       // A: 2 thr/row, float4 each
  const int bn = tid & 127, bk = (tid >> 7) * 4;     // B: 128 cols x 4 k-rows

  float acc[8][8];
#pragma unroll
  for (int i = 0; i < 8; ++i)
#pragma unroll
    for (int j = 0; j < 8; ++j) acc[i][j] = 0.f;

  for (int k0 = 0; k0 < K; k0 += 8) {
    const float4 av = *(const float4*)(A + (size_t)(m0 + ar) * K + k0 + ak);
    const float* wp = W + (size_t)(k0 + bk) * Nw + n0 + bn;
    const float b0 = wp[0];
    const float b1 = wp[Nw];
    const float b2 = wp[2 * (size_t)Nw];
    const float b3 = wp[3 * (size_t)Nw];
    __syncthreads();               // previous iter done reading LDS
    As[ak + 0][ar] = av.x; As[ak + 1][ar] = av.y;
    As[ak + 2][ar] = av.z; As[ak + 3][ar] = av.w;
    Bs[bk + 0][bn] = b0; Bs[bk + 1][bn] = b1;
    Bs[bk + 2][bn] = b2; Bs[bk + 3][bn] = b3;
    __syncthreads();
#pragma unroll
    for (int k = 0; k < 8; ++k) {
      float4 a0 = *(const float4*)&As[k][tm * 8];
      float4 a1 = *(const float4*)&As[k][tm * 8 + 4];
      float4 bb0 = *(const float4*)&Bs[k][tn * 8];
      float4 bb1 = *(const float4*)&Bs[k][tn * 8 + 4];
      float avr[8] = {a0.x, a0.y, a0.z, a0.w, a1.x, a1.y, a1.z, a1.w};
      float bvr[8] = {bb0.x, bb0.y, bb0.z, bb0.w, bb1.x, bb1.y, bb1.z, bb1.w};
#pragma unroll
      for (int i = 0; i < 8; ++i)
#pragma unroll
        for (int j = 0; j < 8; ++j) acc[i][j] += avr[i] * bvr[j];
    }
  }

#pragma unroll
  for (int i = 0; i < 8; ++i) {
    float* crow = C + (size_t)(m0 + tm * 8 + i) * ldc + ccol0 + n0 + tn * 8;
    *(float4*)crow       = make_float4(acc[i][0], acc[i][1], acc[i][2], acc[i][3]);
    *(float4*)(crow + 4) = make_float4(acc[i][4], acc[i][5], acc[i][6], acc[i][7]);
  }
}

__global__ __launch_bounds__(256) void qkv_gemm_kernel(
    const float* __restrict__ x, const float* __restrict__ wq,
    const float* __restrict__ wk, const float* __restrict__ wv,
    float* __restrict__ y) {
  const int by = blockIdx.y;
  const float* W; int Nw, ccol0, n0;
  if (by < 16)      { W = wq; Nw = 2048; ccol0 = 0;    n0 = by * 128; }
  else if (by < 20) { W = wk; Nw = 512;  ccol0 = 2048; n0 = (by - 16) * 128; }
  else              { W = wv; Nw = 512;  ccol0 = 2560; n0 = (by - 20) * 128; }
  sgemm_body(x, W, y, DEMB, Nw, NQKV, ccol0, blockIdx.x * 128, n0);
}

__global__ __launch_bounds__(256) void oproj_gemm_kernel(
    const float* __restrict__ mid, const float* __restrict__ wo,
    float* __restrict__ out) {
  sgemm_body(mid, wo, out, DEMB, DEMB, DEMB, 0, blockIdx.x * 128, blockIdx.y * 128);
}

// ---------------------------------------------------------------------------
// RoPE: ropes q (in place, cols 0..2047 of y) and k (cols 2048..2559 -> kv
// cache), copies v (cols 2560..3071 -> kv cache). One block per (b,t).
// kv cache layout: [B,T,4,256] with k in [0:128], v in [128:256].
// ---------------------------------------------------------------------------
__device__ __forceinline__ void rope_trig(int ti, int dd, float& c, float& s) {
  // theta = 10000^(-2*dd/128); tick computed as f32*f32 like the reference,
  // then sin/cos in double of that f32 value (ref is f32 sin/cos; diff ~1e-7)
  double theta = exp((double)(-2 * dd) * (9.210340371976184 / 128.0)); // ln(1e4)
  float tickf = (float)ti * (float)theta;
  c = (float)cos((double)tickf);
  s = (float)sin((double)tickf);
}

__global__ __launch_bounds__(256) void rope_kernel(float* __restrict__ y,
                                                   float* __restrict__ kvout) {
  const int bt = blockIdx.x;        // b*2048 + ti
  const int ti = bt & (TLEN - 1);
  float* yr = y + (size_t)bt * NQKV;
  float* kvr = kvout + (size_t)bt * (NHKV * 256);
  for (int idx = threadIdx.x; idx < 1792; idx += 256) {
    if (idx < 1024) {               // q: 16 heads x 64 pairs
      int qh = idx >> 6, dd = idx & 63;
      float* p = yr + qh * 128;
      float c, s; rope_trig(ti, dd, c, s);
      float a = p[dd], b2 = p[dd + 64];
      p[dd]      = a * c - b2 * s;
      p[dd + 64] = b2 * c + a * s;
    } else if (idx < 1280) {        // k: 4 heads x 64 pairs -> kv cache
      int r = idx - 1024; int h = r >> 6, dd = r & 63;
      const float* p = yr + 2048 + h * 128;
      float c, s; rope_trig(ti, dd, c, s);
      float a = p[dd], b2 = p[dd + 64];
      float* q = kvr + h * 256;
      q[dd]      = a * c - b2 * s;
      q[dd + 64] = b2 * c + a * s;
    } else {                        // v: 4 heads x 128 copies
      int r = idx - 1280; int h = r >> 7, dd = r & 127;
      kvr[h * 256 + 128 + dd] = yr[2560 + h * 128 + dd];
    }
  }
}

// ---------------------------------------------------------------------------
// Attention: one block per (b, kv_head h, ti); computes all 4 grouped q-heads
// (qh = g*4+h). Scores+softmax+exact-dropout+PV. K/V read from the kv-cache
// region of d_out (already written by rope_kernel).
// ---------------------------------------------------------------------------
__global__ __launch_bounds__(256) void attn_kernel(const float* __restrict__ y,
                                                   const float* __restrict__ kv,
                                                   float* __restrict__ mid) {
  __shared__ float sc[4][2048];
  __shared__ float qs[4][128];
  __shared__ float wred[4];
  __shared__ float sinv[4];
  __shared__ float pvred[256];

  const int tid = threadIdx.x;
  const int blk = blockIdx.x;
  const int ti = blk & (TLEN - 1);
  const int bh = blk >> 11;          // 0..7
  const int h = bh & 3, b = bh >> 2;
  const size_t bt = (size_t)b * TLEN + ti;

  for (int idx = tid; idx < 512; idx += 256) {
    int g = idx >> 7, d = idx & 127;
    qs[g][d] = y[bt * NQKV + (size_t)((g * 4 + h) * 128 + d)];
  }
  __syncthreads();

  const float scale = 0.08838834764831843f;   // 1/sqrt(128)
  const float* kvb = kv + ((size_t)b * TLEN * 4 + h) * 256;  // + tj*1024 + d

  // ---- scores: 4 tj per thread per 1024-chunk ----
  for (int base = 0; base <= ti; base += 1024) {
    int tj[4]; const float* kp[4]; bool val[4];
    float acc[4][4];
#pragma unroll
    for (int g = 0; g < 4; ++g)
#pragma unroll
      for (int jj = 0; jj < 4; ++jj) acc[g][jj] = 0.f;
#pragma unroll
    for (int jj = 0; jj < 4; ++jj) {
      tj[jj] = base + jj * 256 + tid;
      val[jj] = (tj[jj] <= ti);
      kp[jj] = kvb + (size_t)(val[jj] ? tj[jj] : 0) * 1024;
    }
    for (int d = 0; d < 128; d += 4) {
      float4 q0 = *(const float4*)&qs[0][d];
      float4 q1 = *(const float4*)&qs[1][d];
      float4 q2 = *(const float4*)&qs[2][d];
      float4 q3 = *(const float4*)&qs[3][d];
#pragma unroll
      for (int jj = 0; jj < 4; ++jj) {
        float4 kk = *(const float4*)(kp[jj] + d);
        acc[0][jj] += q0.x*kk.x + q0.y*kk.y + q0.z*kk.z + q0.w*kk.w;
        acc[1][jj] += q1.x*kk.x + q1.y*kk.y + q1.z*kk.z + q1.w*kk.w;
        acc[2][jj] += q2.x*kk.x + q2.y*kk.y + q2.z*kk.z + q2.w*kk.w;
        acc[3][jj] += q3.x*kk.x + q3.y*kk.y + q3.z*kk.z + q3.w*kk.w;
      }
    }
#pragma unroll
    for (int jj = 0; jj < 4; ++jj)
      if (val[jj]) {
#pragma unroll
        for (int g = 0; g < 4; ++g) sc[g][tj[jj]] = acc[g][jj] * scale;
      }
  }
  __syncthreads();

  // ---- softmax + dropout per head-group g ----
  for (int g = 0; g < 4; ++g) {
    float m = -1e30f;
    for (int t2 = tid; t2 <= ti; t2 += 256) m = fmaxf(m, sc[g][t2]);
#pragma unroll
    for (int o = 32; o > 0; o >>= 1) m = fmaxf(m, __shfl_down(m, o));
    if ((tid & 63) == 0) wred[tid >> 6] = m;
    __syncthreads();
    m = fmaxf(fmaxf(wred[0], wred[1]), fmaxf(wred[2], wred[3]));
    __syncthreads();

    float sum = 0.f;
    for (int t2 = tid; t2 <= ti; t2 += 256) {
      float e = expf(sc[g][t2] - m);
      sc[g][t2] = e;
      sum += e;
    }
#pragma unroll
    for (int o = 32; o > 0; o >>= 1) sum += __shfl_down(sum, o);
    if ((tid & 63) == 0) wred[tid >> 6] = sum;
    __syncthreads();
    sum = wred[0] + wred[1] + wred[2] + wred[3];
    if (tid == 0) sinv[g] = 1.0f / sum;
    __syncthreads();

    // exact JAX dropout mask
    const uint32_t ib = ((uint32_t)((b * 4 + g) * 4 + h) * 2048u + (uint32_t)ti) * 2048u;
    for (int t2 = tid; t2 <= ti; t2 += 256) {
      uint32_t bits = threefry_bits(ib + (uint32_t)t2);
      float u = __uint_as_float((bits >> 9) | 0x3f800000u) - 1.0f;
      if (!(u < 0.9f)) sc[g][t2] = 0.f;
    }
    __syncthreads();
  }

  // ---- PV: V read once, used by all 4 groups ----
  const int vd = tid & 127, hf = tid >> 7;
  float a0 = 0.f, a1 = 0.f, a2 = 0.f, a3 = 0.f;
  const float* vb = kv + ((size_t)b * TLEN * 4 + h) * 256 + 128 + vd;
  for (int t2 = hf; t2 <= ti; t2 += 2) {
    float vv = vb[(size_t)t2 * 1024];
    a0 += sc[0][t2] * vv;
    a1 += sc[1][t2] * vv;
    a2 += sc[2][t2] * vv;
    a3 += sc[3][t2] * vv;
  }
  float accs[4] = {a0, a1, a2, a3};
  const float inv09 = 1.0f / 0.9f;
#pragma unroll
  for (int g = 0; g < 4; ++g) {
    pvred[tid] = accs[g];
    __syncthreads();
    if (tid < 128) {
      float o = (pvred[tid] + pvred[tid + 128]) * sinv[g] * inv09;
      mid[bt * DEMB + (size_t)((g * 4 + h) * 128) + vd] = o;
    }
    __syncthreads();
  }
}

// ---------------------------------------------------------------------------
extern "C" void kernel_launch(void* const* d_in, const int* in_sizes, int n_in,
                              void* d_out, int out_size, void* d_ws, size_t ws_size,
                              hipStream_t stream) {
  const float* x  = (const float*)d_in[0];
  const float* wq = (const float*)d_in[1];
  const float* wk = (const float*)d_in[2];
  const float* wv = (const float*)d_in[3];
  const float* wo = (const float*)d_in[4];
  float* out = (float*)d_out;
  float* kvc = out + ATTN_OUT_ELEMS;                 // [B,T,4,256]
  float* y   = (float*)d_ws;                         // [4096][3072] raw qkv (q roped in place)
  float* mid = y + (size_t)(BATCH * TLEN) * NQKV;    // [4096][2048] attn out pre-proj

  dim3 blk(256);
  qkv_gemm_kernel<<<dim3(32, 24), blk, 0, stream>>>(x, wq, wk, wv, y);
  rope_kernel<<<dim3(BATCH * TLEN), blk, 0, stream>>>(y, kvc);
  attn_kernel<<<dim3(BATCH * NHKV * TLEN), blk, 0, stream>>>(y, kvc, mid);
  oproj_gemm_kernel<<<dim3(32, 16), blk, 0, stream>>>(mid, wo, out);
}

// Round 3
// 565.338 us; speedup vs baseline: 6.1841x; 6.1841x over previous
//
#include <hip/hip_runtime.h>
#include <stdint.h>

// Problem constants (fixed by reference)
#define BATCH 2
#define TLEN  2048
#define DEMB  2048
#define NHQ   16
#define NHKV  4
#define GRP   4
#define DKV   128
#define ATTN_OUT_ELEMS (BATCH*TLEN*DEMB) // 8388608
// d_out layout: [attn_output (8388608 f32) | kv_cache (B,T,4,256) f32 (4194304)]

typedef __bf16 bf16_t;
typedef __attribute__((ext_vector_type(4))) __bf16 bf16x4;
typedef __attribute__((ext_vector_type(8))) __bf16 bf16x8;
typedef __attribute__((ext_vector_type(4))) float f32x4;

__device__ __forceinline__ f32x4 mfma16(bf16x8 a, bf16x8 b, f32x4 c) {
  return __builtin_amdgcn_mfma_f32_16x16x32_bf16(a, b, c, 0, 0, 0);
}

typedef __attribute__((address_space(1))) const unsigned int as1_uint;
typedef __attribute__((address_space(3))) unsigned int as3_uint;
__device__ __forceinline__ void gload_lds16(const void* g, void* l) {
  // 16B per lane, LDS dest = l + lane*16 (wave-uniform base)
  __builtin_amdgcn_global_load_lds((as1_uint*)g, (as3_uint*)l, 16, 0, 0);
}

// ---------------------------------------------------------------------------
// threefry2x32-20, key=(0,1) (jax.random.key(1)), partitionable mode:
// per-element u64 counter (hi=0, lo=ctr), output = x0 ^ x1. Verified R1.
// ---------------------------------------------------------------------------
__device__ __forceinline__ void tf_round(uint32_t& x0, uint32_t& x1, int r) {
  x0 += x1;
  x1 = (x1 << r) | (x1 >> (32 - r));
  x1 ^= x0;
}
__device__ __forceinline__ uint32_t threefry_bits(uint32_t ctr) {
  const uint32_t ks1 = 1u, ks2 = 0x1BD11BDBu;
  uint32_t x0 = 0u, x1 = ctr + ks1;
  tf_round(x0,x1,13); tf_round(x0,x1,15); tf_round(x0,x1,26); tf_round(x0,x1,6);
  x0 += ks1; x1 += ks2 + 1u;
  tf_round(x0,x1,17); tf_round(x0,x1,29); tf_round(x0,x1,16); tf_round(x0,x1,24);
  x0 += ks2; x1 += 0u + 2u;
  tf_round(x0,x1,13); tf_round(x0,x1,15); tf_round(x0,x1,26); tf_round(x0,x1,6);
  x0 += 0u;  x1 += ks1 + 3u;
  tf_round(x0,x1,17); tf_round(x0,x1,29); tf_round(x0,x1,16); tf_round(x0,x1,24);
  x0 += ks1; x1 += ks2 + 4u;
  tf_round(x0,x1,13); tf_round(x0,x1,15); tf_round(x0,x1,26); tf_round(x0,x1,6);
  x0 += ks2; x1 += 0u + 5u;
  return x0 ^ x1;
}

// ---------------------------------------------------------------------------
// RoPE cos/sin tables [ti=2048][d=64], double-precision generation (matches
// the R1-passing rope_trig maths).
// ---------------------------------------------------------------------------
__global__ __launch_bounds__(256) void rope_tab(float* __restrict__ ct,
                                                float* __restrict__ st) {
  int i = blockIdx.x * 256 + threadIdx.x;     // 131072 total
  int ti = i >> 6, d = i & 63;
  double theta = exp((double)(-2 * d) * (9.210340371976184 / 128.0)); // ln(1e4)/128
  float tick = (float)ti * (float)theta;
  ct[i] = (float)cos((double)tick);
  st[i] = (float)sin((double)tick);
}

// ---------------------------------------------------------------------------
// fp32 -> bf16 convert (X)
// ---------------------------------------------------------------------------
__global__ __launch_bounds__(256) void cvt_bf16(const float* __restrict__ src,
                                                bf16_t* __restrict__ dst, int n4) {
  int i = (blockIdx.x * 256 + threadIdx.x);
  if (i < n4) {
    float4 v = *(const float4*)(src + (size_t)i * 4);
    bf16x4 o = {(bf16_t)v.x, (bf16_t)v.y, (bf16_t)v.z, (bf16_t)v.w};
    *(bf16x4*)(dst + (size_t)i * 4) = o;
  }
}

// ---------------------------------------------------------------------------
// Weight transpose+convert: src f32 [K][N] -> dst bf16 [N][Kd] (dst pre-offset)
// ---------------------------------------------------------------------------
__global__ __launch_bounds__(256) void wtrans(const float* __restrict__ src,
                                              bf16_t* __restrict__ dst,
                                              int N, int Kd) {
  __shared__ float t[64][65];
  const int k0 = blockIdx.x * 64, n0 = blockIdx.y * 64;
  const int tid = threadIdx.x;
  const int r = tid >> 4, c4 = tid & 15;
#pragma unroll
  for (int i = 0; i < 4; ++i) {
    float4 v = *(const float4*)(src + (size_t)(k0 + r + i * 16) * N + n0 + c4 * 4);
    t[r + i * 16][c4 * 4 + 0] = v.x; t[r + i * 16][c4 * 4 + 1] = v.y;
    t[r + i * 16][c4 * 4 + 2] = v.z; t[r + i * 16][c4 * 4 + 3] = v.w;
  }
  __syncthreads();
#pragma unroll
  for (int i = 0; i < 4; ++i) {
    int idx = tid + i * 256;
    int rn = idx >> 4, ck = idx & 15;
    bf16x4 o = {(bf16_t)t[ck * 4 + 0][rn], (bf16_t)t[ck * 4 + 1][rn],
                (bf16_t)t[ck * 4 + 2][rn], (bf16_t)t[ck * 4 + 3][rn]};
    *(bf16x4*)(dst + (size_t)(n0 + rn) * Kd + k0 + ck * 4) = o;
  }
}

// ---------------------------------------------------------------------------
// bf16 MFMA GEMM: C[M,N] = Ab[M,K] (row-major) @ Wt[N,K]^T
// 128x128 tile, BK=64, 4 waves, 64x64/wave; col-tile pairing keeps RoPE
// partners (d, d+64) in-wave for MODE 1. global_load_lds(16B) staging with
// XOR chunk swizzle. MODE 0: f32 C. MODE 1: QKV epilogue (RoPE via tables).
// ---------------------------------------------------------------------------
template<int MODE>
__global__ __launch_bounds__(256) void gemm_bf16(
    const bf16_t* __restrict__ Ab, const bf16_t* __restrict__ Wt,
    float* __restrict__ Cout, bf16_t* __restrict__ qbuf,
    bf16_t* __restrict__ Kbuf, float* __restrict__ kvout,
    const float* __restrict__ costab, const float* __restrict__ sintab,
    int M, int N, int K) {
  __shared__ bf16_t As[128 * 64];
  __shared__ bf16_t Bs[128 * 64];
  const int tid = threadIdx.x;
  const int w = tid >> 6, lane = tid & 63;
  const int lm = lane & 15, lg = lane >> 4;
  const int wy = w & 1, wx = w >> 1;
  const int mblk = blockIdx.x * 128, nblk = blockIdx.y * 128;

  const int srow = lane >> 3;                 // row within 8-row group
  const int schunk = (lane & 7) ^ srow;       // fetch swizzled chunk
  const bf16_t* Ag = Ab + (size_t)(mblk + w * 32 + srow) * K + schunk * 8;
  const bf16_t* Bg = Wt + (size_t)(nblk + w * 32 + srow) * K + schunk * 8;
  bf16_t* AsW = As + (w * 32) * 64;
  bf16_t* BsW = Bs + (w * 32) * 64;

  f32x4 acc[4][4];
#pragma unroll
  for (int i = 0; i < 4; ++i)
#pragma unroll
    for (int j = 0; j < 4; ++j) acc[i][j] = (f32x4)0.0f;

  const int tcol0 = wx * 2;

  for (int k0 = 0; k0 < K; k0 += 64) {
    __syncthreads();
#pragma unroll
    for (int inst = 0; inst < 4; ++inst) {
      gload_lds16(Ag + (size_t)(inst * 8) * K + k0, AsW + inst * 8 * 64);
      gload_lds16(Bg + (size_t)(inst * 8) * K + k0, BsW + inst * 8 * 64);
    }
    asm volatile("s_waitcnt vmcnt(0)" ::: "memory");
    __syncthreads();
#pragma unroll
    for (int ks = 0; ks < 2; ++ks) {
      const int chunk = ((ks * 4 + lg) ^ (lane & 7)) * 8;
      bf16x8 af[4], bfr[4];
#pragma unroll
      for (int i = 0; i < 4; ++i) {
        int mrow = wy * 64 + i * 16 + lm;
        af[i] = *(const bf16x8*)&As[mrow * 64 + chunk];
      }
#pragma unroll
      for (int j = 0; j < 4; ++j) {
        int tc = tcol0 + (j & 1) + (j >> 1) * 4;
        int nrow = tc * 16 + lm;
        bfr[j] = *(const bf16x8*)&Bs[nrow * 64 + chunk];
      }
#pragma unroll
      for (int i = 0; i < 4; ++i)
#pragma unroll
        for (int j = 0; j < 4; ++j) acc[i][j] = mfma16(af[i], bfr[j], acc[i][j]);
    }
  }

  if (MODE == 0) {
#pragma unroll
    for (int i = 0; i < 4; ++i)
#pragma unroll
      for (int j = 0; j < 4; ++j) {
        int tc = tcol0 + (j & 1) + (j >> 1) * 4;
        int col = nblk + tc * 16 + lm;
#pragma unroll
        for (int r = 0; r < 4; ++r) {
          int row = mblk + wy * 64 + i * 16 + lg * 4 + r;
          Cout[(size_t)row * N + col] = acc[i][j][r];
        }
      }
  } else {
    // QKV epilogue with fused RoPE via tables. d in [0,64), partner d+64.
    const float qscale = 0.08838834764831843f;   // 1/sqrt(128)
#pragma unroll
    for (int i = 0; i < 4; ++i) {
#pragma unroll
      for (int r = 0; r < 4; ++r) {
        int row = mblk + wy * 64 + i * 16 + lg * 4 + r;   // bt
        int ti = row & (TLEN - 1), b = row >> 11;
#pragma unroll
        for (int jp = 0; jp < 2; ++jp) {
          float lo = acc[i][jp][r], hi = acc[i][jp + 2][r];
          int d = wx * 32 + jp * 16 + lm;                 // [0,64)
          int nl = nblk + d;                              // low-half global col
          if (nblk < 2048) {                              // q
            int qh = nl >> 7;
            float cs = costab[ti * 64 + d], sn = sintab[ti * 64 + d];
            float o0 = (lo * cs - hi * sn) * qscale;
            float o1 = (hi * cs + lo * sn) * qscale;
            size_t qo = (((size_t)(b * 16 + qh)) * TLEN + ti) * 128 + d;
            qbuf[qo] = (bf16_t)o0; qbuf[qo + 64] = (bf16_t)o1;
          } else if (nblk < 2560) {                       // k
            int hh = (nl - 2048) >> 7;
            float cs = costab[ti * 64 + d], sn = sintab[ti * 64 + d];
            float o0 = lo * cs - hi * sn;
            float o1 = hi * cs + lo * sn;
            size_t ko = (((size_t)(b * 4 + hh)) * TLEN + ti) * 128 + d;
            Kbuf[ko] = (bf16_t)o0; Kbuf[ko + 64] = (bf16_t)o1;
            size_t kvo = (size_t)row * 1024 + hh * 256 + d;
            kvout[kvo] = o0; kvout[kvo + 64] = o1;
          } else {                                        // v
            int hh = (nl - 2560) >> 7;
            size_t kvo = (size_t)row * 1024 + hh * 256 + 128 + d;
            kvout[kvo] = lo; kvout[kvo + 64] = hi;
          }
        }
      }
    }
  }
}

// ---------------------------------------------------------------------------
// V transpose: kv f32 [b][ti][h][128v @ +128] -> Vtb bf16 [b][h][d=128][tj=2048]
// ---------------------------------------------------------------------------
__global__ __launch_bounds__(256) void vtrans(const float* __restrict__ kvout,
                                              bf16_t* __restrict__ Vtb) {
  __shared__ bf16_t t[128][72];
  const int bx = blockIdx.x;          // (b*4+h)*32 + tt
  const int tt = bx & 31, bh = bx >> 5;
  const int b = bh >> 2, h = bh & 3;
  const int ti0 = tt * 64;
  const float* src = kvout + ((size_t)b * TLEN + ti0) * 1024 + h * 256 + 128;
  for (int idx = threadIdx.x; idx < 64 * 32; idx += 256) {
    int ti = idx >> 5, c4 = idx & 31;
    float4 v = *(const float4*)(src + (size_t)ti * 1024 + c4 * 4);
    t[c4 * 4 + 0][ti] = (bf16_t)v.x; t[c4 * 4 + 1][ti] = (bf16_t)v.y;
    t[c4 * 4 + 2][ti] = (bf16_t)v.z; t[c4 * 4 + 3][ti] = (bf16_t)v.w;
  }
  __syncthreads();
  bf16_t* dst = Vtb + (size_t)bh * 128 * TLEN + ti0;
  for (int idx = threadIdx.x; idx < 128 * 16; idx += 256) {
    int d = idx >> 4, ck = idx & 15;
    bf16x4 o = {t[d][ck * 4 + 0], t[d][ck * 4 + 1], t[d][ck * 4 + 2], t[d][ck * 4 + 3]};
    *(bf16x4*)(dst + (size_t)d * TLEN + ck * 4) = o;
  }
}

// ---------------------------------------------------------------------------
// Flash attention, bf16 MFMA. Block = (b, qh, 128-row q-tile), 4 waves,
// wave w owns 32 rows. 64-col K-tiles, no barriers in K-loop (wave-private
// LDS strip for P C->A relayout). Online softmax via 16-lane shfl_xor.
// Exact JAX dropout on P after l-accumulation (pre-normalization).
// blockIdx pairing: bx and bx+256 get q-tiles t and 15-t (uniform CU load).
// ---------------------------------------------------------------------------
__global__ __launch_bounds__(256, 2) void attn_flash(
    const bf16_t* __restrict__ qb, const bf16_t* __restrict__ Kb,
    const bf16_t* __restrict__ Vtb, bf16_t* __restrict__ midb) {
  __shared__ bf16_t P_lds[128 * 72];
  const int tid = threadIdx.x;
  const int w = tid >> 6, lane = tid & 63;
  const int lm = lane & 15, lg = lane >> 4;

  const int bx = blockIdx.x;
  const int bhalf = bx >> 8, r8 = bx & 255;
  const int qh = r8 & 15, b = (r8 >> 4) & 1, t3 = r8 >> 5;
  const int qt = bhalf ? (15 - t3) : t3;
  const int h = qh & 3, g = qh >> 2;

  const bf16_t* qbase = qb + (((size_t)(b * 16 + qh)) * TLEN + qt * 128) * 128;
  const bf16_t* kbase = Kb + ((size_t)(b * 4 + h)) * TLEN * 128;
  const bf16_t* vbase = Vtb + ((size_t)(b * 4 + h)) * 128 * TLEN;

  // Q A-frags (rows w*32 + it*16 + lm); q already scaled by 1/sqrt(128)
  bf16x8 qf[2][4];
#pragma unroll
  for (int it = 0; it < 2; ++it)
#pragma unroll
    for (int kk = 0; kk < 4; ++kk)
      qf[it][kk] = *(const bf16x8*)(qbase + (size_t)(w * 32 + it * 16 + lm) * 128 + kk * 32 + lg * 8);

  float mrow[2][4], lrow[2][4];
  f32x4 Oacc[2][8];
#pragma unroll
  for (int it = 0; it < 2; ++it) {
#pragma unroll
    for (int r = 0; r < 4; ++r) { mrow[it][r] = -3.0e38f; lrow[it][r] = 0.f; }
#pragma unroll
    for (int c = 0; c < 8; ++c) Oacc[it][c] = (f32x4)0.0f;
  }

  const int row0 = qt * 128 + w * 32;          // wave's first q row
  const int nkt = (row0 + 31) / 64 + 1;        // K-tiles this wave needs
  const float L2E = 1.4426950408889634f;
  const uint32_t hdr = (uint32_t)((b * 4 + g) * 4 + h);

  for (int kt = 0; kt < nkt; ++kt) {
    const int tj0 = kt * 64;
    // ---- S = Q K^T ----
    f32x4 S[2][4];
#pragma unroll
    for (int it = 0; it < 2; ++it)
#pragma unroll
      for (int ct = 0; ct < 4; ++ct) S[it][ct] = (f32x4)0.0f;
#pragma unroll
    for (int ct = 0; ct < 4; ++ct) {
      bf16x8 kf[4];
#pragma unroll
      for (int kk = 0; kk < 4; ++kk)
        kf[kk] = *(const bf16x8*)(kbase + (size_t)(tj0 + ct * 16 + lm) * 128 + kk * 32 + lg * 8);
#pragma unroll
      for (int it = 0; it < 2; ++it)
#pragma unroll
        for (int kk = 0; kk < 4; ++kk) S[it][ct] = mfma16(qf[it][kk], kf[kk], S[it][ct]);
    }

    // ---- causal mask (diagonal tiles only) ----
    if (tj0 + 63 > row0) {
#pragma unroll
      for (int it = 0; it < 2; ++it)
#pragma unroll
        for (int ct = 0; ct < 4; ++ct) {
          int tj = tj0 + ct * 16 + lm;
#pragma unroll
          for (int r = 0; r < 4; ++r) {
            int ti = row0 + it * 16 + lg * 4 + r;
            if (tj > ti) S[it][ct][r] = -1.0e30f;
          }
        }
    }

    // ---- online softmax ----
    float alpha[2][4];
#pragma unroll
    for (int it = 0; it < 2; ++it) {
      float pm[4];
#pragma unroll
      for (int r = 0; r < 4; ++r)
        pm[r] = fmaxf(fmaxf(S[it][0][r], S[it][1][r]), fmaxf(S[it][2][r], S[it][3][r]));
#pragma unroll
      for (int off = 1; off < 16; off <<= 1)
#pragma unroll
        for (int r = 0; r < 4; ++r) pm[r] = fmaxf(pm[r], __shfl_xor(pm[r], off));
#pragma unroll
      for (int r = 0; r < 4; ++r) {
        float mn = fmaxf(mrow[it][r], pm[r]);
        alpha[it][r] = exp2f((mrow[it][r] - mn) * L2E);
        mrow[it][r] = mn;
      }
      // P = exp(S - m), rowsum BEFORE dropout
      float rs[4] = {0.f, 0.f, 0.f, 0.f};
#pragma unroll
      for (int ct = 0; ct < 4; ++ct)
#pragma unroll
        for (int r = 0; r < 4; ++r) {
          float p = exp2f((S[it][ct][r] - mrow[it][r]) * L2E);
          S[it][ct][r] = p;
          rs[r] += p;
        }
#pragma unroll
      for (int off = 1; off < 16; off <<= 1)
#pragma unroll
        for (int r = 0; r < 4; ++r) rs[r] += __shfl_xor(rs[r], off);
#pragma unroll
      for (int r = 0; r < 4; ++r) lrow[it][r] = lrow[it][r] * alpha[it][r] + rs[r];
    }

    // ---- dropout + bf16 + LDS (C-layout -> A-layout staging) ----
#pragma unroll
    for (int it = 0; it < 2; ++it)
#pragma unroll
      for (int r = 0; r < 4; ++r) {
        int ti = row0 + it * 16 + lg * 4 + r;
        uint32_t cb = (hdr << 22) + ((uint32_t)ti << 11) + (uint32_t)tj0;
        int prow = (w * 32 + it * 16 + lg * 4 + r) * 72 + lm;
#pragma unroll
        for (int ct = 0; ct < 4; ++ct) {
          uint32_t bits = threefry_bits(cb + (uint32_t)(ct * 16 + lm));
          float u = __uint_as_float((bits >> 9) | 0x3f800000u) - 1.0f;
          float p = (u < 0.9f) ? S[it][ct][r] : 0.f;
          P_lds[prow + ct * 16] = (bf16_t)p;
        }
      }
    asm volatile("s_waitcnt lgkmcnt(0)" ::: "memory");

    // ---- O = O*alpha + P V ----
#pragma unroll
    for (int it = 0; it < 2; ++it)
#pragma unroll
      for (int c = 0; c < 8; ++c)
#pragma unroll
        for (int r = 0; r < 4; ++r) Oacc[it][c][r] *= alpha[it][r];

    bf16x8 aP[2][2];
#pragma unroll
    for (int it = 0; it < 2; ++it)
#pragma unroll
      for (int kk = 0; kk < 2; ++kk)
        aP[it][kk] = *(const bf16x8*)&P_lds[(w * 32 + it * 16 + lm) * 72 + kk * 32 + lg * 8];
#pragma unroll
    for (int c = 0; c < 8; ++c) {
      bf16x8 vf[2];
#pragma unroll
      for (int kk = 0; kk < 2; ++kk)
        vf[kk] = *(const bf16x8*)(vbase + (size_t)(c * 16 + lm) * TLEN + tj0 + kk * 32 + lg * 8);
#pragma unroll
      for (int it = 0; it < 2; ++it)
#pragma unroll
        for (int kk = 0; kk < 2; ++kk) Oacc[it][c] = mfma16(aP[it][kk], vf[kk], Oacc[it][c]);
    }
  }

  // ---- epilogue: normalize (1/l) * (1/0.9), write bf16 mid ----
#pragma unroll
  for (int it = 0; it < 2; ++it) {
    float invl[4];
#pragma unroll
    for (int r = 0; r < 4; ++r) invl[r] = (1.0f / 0.9f) / lrow[it][r];
#pragma unroll
    for (int c = 0; c < 8; ++c) {
      int d = c * 16 + lm;
#pragma unroll
      for (int r = 0; r < 4; ++r) {
        int bt = b * TLEN + qt * 128 + w * 32 + it * 16 + lg * 4 + r;
        midb[(size_t)bt * DEMB + qh * 128 + d] = (bf16_t)(Oacc[it][c][r] * invl[r]);
      }
    }
  }
}

// ---------------------------------------------------------------------------
extern "C" void kernel_launch(void* const* d_in, const int* in_sizes, int n_in,
                              void* d_out, int out_size, void* d_ws, size_t ws_size,
                              hipStream_t stream) {
  const float* x  = (const float*)d_in[0];
  const float* wq = (const float*)d_in[1];
  const float* wk = (const float*)d_in[2];
  const float* wv = (const float*)d_in[3];
  const float* wo = (const float*)d_in[4];
  float* out = (float*)d_out;
  float* kvc = out + ATTN_OUT_ELEMS;                    // [B,T,4,256] f32

  // workspace carve-up (~80.8 MB)
  char* ws = (char*)d_ws;
  bf16_t* Xb     = (bf16_t*)ws;                          ws += (size_t)4096 * 2048 * 2;  // 16.8MB
  bf16_t* Wqkvt  = (bf16_t*)ws;                          ws += (size_t)3072 * 2048 * 2;  // 12.6MB
  bf16_t* Wot    = (bf16_t*)ws;                          ws += (size_t)2048 * 2048 * 2;  // 8.4MB
  bf16_t* qbuf   = (bf16_t*)ws;                          ws += (size_t)2 * 16 * 2048 * 128 * 2; // 16.8MB
  bf16_t* Kbuf   = (bf16_t*)ws;                          ws += (size_t)2 * 4 * 2048 * 128 * 2;  // 4.2MB
  bf16_t* Vtb    = (bf16_t*)ws;                          ws += (size_t)2 * 4 * 128 * 2048 * 2;  // 4.2MB
  bf16_t* midb   = (bf16_t*)ws;                          ws += (size_t)4096 * 2048 * 2;  // 16.8MB
  float*  costab = (float*)ws;                           ws += (size_t)2048 * 64 * 4;    // 0.5MB
  float*  sintab = (float*)ws;                           // 0.5MB

  dim3 blk(256);
  rope_tab<<<512, blk, 0, stream>>>(costab, sintab);
  cvt_bf16<<<8192, blk, 0, stream>>>(x, Xb, 8388608 / 4);
  wtrans<<<dim3(32, 32), blk, 0, stream>>>(wq, Wqkvt, 2048, 2048);
  wtrans<<<dim3(32, 8),  blk, 0, stream>>>(wk, Wqkvt + (size_t)2048 * 2048, 512, 2048);
  wtrans<<<dim3(32, 8),  blk, 0, stream>>>(wv, Wqkvt + (size_t)2560 * 2048, 512, 2048);
  wtrans<<<dim3(32, 32), blk, 0, stream>>>(wo, Wot, 2048, 2048);

  gemm_bf16<1><<<dim3(32, 24), blk, 0, stream>>>(Xb, Wqkvt, nullptr, qbuf, Kbuf, kvc,
                                                 costab, sintab, 4096, 3072, 2048);
  vtrans<<<dim3(256), blk, 0, stream>>>(kvc, Vtb);
  attn_flash<<<dim3(512), blk, 0, stream>>>(qbuf, Kbuf, Vtb, midb);
  gemm_bf16<0><<<dim3(32, 16), blk, 0, stream>>>(midb, Wot, out, nullptr, nullptr, nullptr,
                                                 nullptr, nullptr, 4096, 2048, 2048);
}

// Round 4
// 531.531 us; speedup vs baseline: 6.5774x; 1.0636x over previous
//
#include <hip/hip_runtime.h>
#include <stdint.h>

// Problem constants (fixed by reference)
#define BATCH 2
#define TLEN  2048
#define DEMB  2048
#define NHQ   16
#define NHKV  4
#define GRP   4
#define DKV   128
#define ATTN_OUT_ELEMS (BATCH*TLEN*DEMB) // 8388608
// d_out layout: [attn_output (8388608 f32) | kv_cache (B,T,4,256) f32 (4194304)]

typedef __bf16 bf16_t;
typedef __attribute__((ext_vector_type(4))) __bf16 bf16x4;
typedef __attribute__((ext_vector_type(8))) __bf16 bf16x8;
typedef __attribute__((ext_vector_type(4))) float f32x4;

__device__ __forceinline__ f32x4 mfma16(bf16x8 a, bf16x8 b, f32x4 c) {
  return __builtin_amdgcn_mfma_f32_16x16x32_bf16(a, b, c, 0, 0, 0);
}

typedef __attribute__((address_space(1))) const unsigned int as1_uint;
typedef __attribute__((address_space(3))) unsigned int as3_uint;
__device__ __forceinline__ void gload_lds16(const void* g, void* l) {
  // 16B per lane, LDS dest = l + lane*16 (wave-uniform base)
  __builtin_amdgcn_global_load_lds((as1_uint*)g, (as3_uint*)l, 16, 0, 0);
}

// ---------------------------------------------------------------------------
// threefry2x32-20, key=(0,1) (jax.random.key(1)), partitionable mode:
// per-element u64 counter (hi=0, lo=ctr), output = x0 ^ x1. Verified R1.
// keep = uniform<0.9  ⇔  bits < 0xE6666600 (exact bit-level equivalence).
// ---------------------------------------------------------------------------
__device__ __forceinline__ void tf_round(uint32_t& x0, uint32_t& x1, int r) {
  x0 += x1;
  x1 = (x1 << r) | (x1 >> (32 - r));
  x1 ^= x0;
}
__device__ __forceinline__ uint32_t threefry_bits(uint32_t ctr) {
  const uint32_t ks1 = 1u, ks2 = 0x1BD11BDBu;
  uint32_t x0 = 0u, x1 = ctr + ks1;
  tf_round(x0,x1,13); tf_round(x0,x1,15); tf_round(x0,x1,26); tf_round(x0,x1,6);
  x0 += ks1; x1 += ks2 + 1u;
  tf_round(x0,x1,17); tf_round(x0,x1,29); tf_round(x0,x1,16); tf_round(x0,x1,24);
  x0 += ks2; x1 += 0u + 2u;
  tf_round(x0,x1,13); tf_round(x0,x1,15); tf_round(x0,x1,26); tf_round(x0,x1,6);
  x0 += 0u;  x1 += ks1 + 3u;
  tf_round(x0,x1,17); tf_round(x0,x1,29); tf_round(x0,x1,16); tf_round(x0,x1,24);
  x0 += ks1; x1 += ks2 + 4u;
  tf_round(x0,x1,13); tf_round(x0,x1,15); tf_round(x0,x1,26); tf_round(x0,x1,6);
  x0 += ks2; x1 += 0u + 5u;
  return x0 ^ x1;
}

// ---------------------------------------------------------------------------
// RoPE cos/sin tables [ti=2048][d=64] (double-precision generation).
// ---------------------------------------------------------------------------
__global__ __launch_bounds__(256) void rope_tab(float* __restrict__ ct,
                                                float* __restrict__ st) {
  int i = blockIdx.x * 256 + threadIdx.x;     // 131072 total
  int ti = i >> 6, d = i & 63;
  double theta = exp((double)(-2 * d) * (9.210340371976184 / 128.0)); // ln(1e4)/128
  float tick = (float)ti * (float)theta;
  ct[i] = (float)cos((double)tick);
  st[i] = (float)sin((double)tick);
}

// ---------------------------------------------------------------------------
// fp32 -> bf16 convert (X)
// ---------------------------------------------------------------------------
__global__ __launch_bounds__(256) void cvt_bf16(const float* __restrict__ src,
                                                bf16_t* __restrict__ dst, int n4) {
  int i = (blockIdx.x * 256 + threadIdx.x);
  if (i < n4) {
    float4 v = *(const float4*)(src + (size_t)i * 4);
    bf16x4 o = {(bf16_t)v.x, (bf16_t)v.y, (bf16_t)v.z, (bf16_t)v.w};
    *(bf16x4*)(dst + (size_t)i * 4) = o;
  }
}

// ---------------------------------------------------------------------------
// Weight transpose+convert: src f32 [K][N] -> dst bf16 [N][Kd]
// ---------------------------------------------------------------------------
__device__ __forceinline__ void wtrans_body(const float* __restrict__ src,
                                            bf16_t* __restrict__ dst,
                                            int N, int Kd, int k0, int n0) {
  __shared__ float t[64][65];
  const int tid = threadIdx.x;
  const int r = tid >> 4, c4 = tid & 15;
#pragma unroll
  for (int i = 0; i < 4; ++i) {
    float4 v = *(const float4*)(src + (size_t)(k0 + r + i * 16) * N + n0 + c4 * 4);
    t[r + i * 16][c4 * 4 + 0] = v.x; t[r + i * 16][c4 * 4 + 1] = v.y;
    t[r + i * 16][c4 * 4 + 2] = v.z; t[r + i * 16][c4 * 4 + 3] = v.w;
  }
  __syncthreads();
#pragma unroll
  for (int i = 0; i < 4; ++i) {
    int idx = tid + i * 256;
    int rn = idx >> 4, ck = idx & 15;
    bf16x4 o = {(bf16_t)t[ck * 4 + 0][rn], (bf16_t)t[ck * 4 + 1][rn],
                (bf16_t)t[ck * 4 + 2][rn], (bf16_t)t[ck * 4 + 3][rn]};
    *(bf16x4*)(dst + (size_t)(n0 + rn) * Kd + k0 + ck * 4) = o;
  }
}

// merged wq/wk/wv transpose (one dispatch)
__global__ __launch_bounds__(256) void wtrans3(const float* __restrict__ wq,
                                               const float* __restrict__ wk,
                                               const float* __restrict__ wv,
                                               bf16_t* __restrict__ dst) {
  const int by = blockIdx.y, k0 = blockIdx.x * 64;
  if (by < 32)      wtrans_body(wq, dst,                          2048, 2048, k0, by * 64);
  else if (by < 40) wtrans_body(wk, dst + (size_t)2048 * 2048,    512,  2048, k0, (by - 32) * 64);
  else              wtrans_body(wv, dst + (size_t)2560 * 2048,    512,  2048, k0, (by - 40) * 64);
}

__global__ __launch_bounds__(256) void wtrans1(const float* __restrict__ src,
                                               bf16_t* __restrict__ dst,
                                               int N, int Kd) {
  wtrans_body(src, dst, N, Kd, blockIdx.x * 64, blockIdx.y * 64);
}

// ---------------------------------------------------------------------------
// bf16 MFMA GEMM: C[M,N] = Ab[M,K] (row-major) @ Wt[N,K]^T
// 128x128 tile, BK=64, 4 waves, 64x64/wave; col-tile pairing keeps RoPE
// partners (d, d+64) in-wave for MODE 1. global_load_lds(16B) staging with
// XOR chunk swizzle. MODE 0: f32 C. MODE 1: QKV epilogue (RoPE via tables).
// ---------------------------------------------------------------------------
template<int MODE>
__global__ __launch_bounds__(256) void gemm_bf16(
    const bf16_t* __restrict__ Ab, const bf16_t* __restrict__ Wt,
    float* __restrict__ Cout, bf16_t* __restrict__ qbuf,
    bf16_t* __restrict__ Kbuf, float* __restrict__ kvout,
    const float* __restrict__ costab, const float* __restrict__ sintab,
    int M, int N, int K) {
  __shared__ bf16_t As[128 * 64];
  __shared__ bf16_t Bs[128 * 64];
  const int tid = threadIdx.x;
  const int w = tid >> 6, lane = tid & 63;
  const int lm = lane & 15, lg = lane >> 4;
  const int wy = w & 1, wx = w >> 1;
  const int mblk = blockIdx.x * 128, nblk = blockIdx.y * 128;

  const int srow = lane >> 3;                 // row within 8-row group
  const int schunk = (lane & 7) ^ srow;       // fetch swizzled chunk
  const bf16_t* Ag = Ab + (size_t)(mblk + w * 32 + srow) * K + schunk * 8;
  const bf16_t* Bg = Wt + (size_t)(nblk + w * 32 + srow) * K + schunk * 8;
  bf16_t* AsW = As + (w * 32) * 64;
  bf16_t* BsW = Bs + (w * 32) * 64;

  f32x4 acc[4][4];
#pragma unroll
  for (int i = 0; i < 4; ++i)
#pragma unroll
    for (int j = 0; j < 4; ++j) acc[i][j] = (f32x4)0.0f;

  const int tcol0 = wx * 2;

  for (int k0 = 0; k0 < K; k0 += 64) {
    __syncthreads();
#pragma unroll
    for (int inst = 0; inst < 4; ++inst) {
      gload_lds16(Ag + (size_t)(inst * 8) * K + k0, AsW + inst * 8 * 64);
      gload_lds16(Bg + (size_t)(inst * 8) * K + k0, BsW + inst * 8 * 64);
    }
    asm volatile("s_waitcnt vmcnt(0)" ::: "memory");
    __syncthreads();
#pragma unroll
    for (int ks = 0; ks < 2; ++ks) {
      const int chunk = ((ks * 4 + lg) ^ (lane & 7)) * 8;
      bf16x8 af[4], bfr[4];
#pragma unroll
      for (int i = 0; i < 4; ++i) {
        int mrow = wy * 64 + i * 16 + lm;
        af[i] = *(const bf16x8*)&As[mrow * 64 + chunk];
      }
#pragma unroll
      for (int j = 0; j < 4; ++j) {
        int tc = tcol0 + (j & 1) + (j >> 1) * 4;
        int nrow = tc * 16 + lm;
        bfr[j] = *(const bf16x8*)&Bs[nrow * 64 + chunk];
      }
#pragma unroll
      for (int i = 0; i < 4; ++i)
#pragma unroll
        for (int j = 0; j < 4; ++j) acc[i][j] = mfma16(af[i], bfr[j], acc[i][j]);
    }
  }

  if (MODE == 0) {
#pragma unroll
    for (int i = 0; i < 4; ++i)
#pragma unroll
      for (int j = 0; j < 4; ++j) {
        int tc = tcol0 + (j & 1) + (j >> 1) * 4;
        int col = nblk + tc * 16 + lm;
#pragma unroll
        for (int r = 0; r < 4; ++r) {
          int row = mblk + wy * 64 + i * 16 + lg * 4 + r;
          Cout[(size_t)row * N + col] = acc[i][j][r];
        }
      }
  } else {
    // QKV epilogue with fused RoPE via tables. d in [0,64), partner d+64.
    const float qscale = 0.08838834764831843f;   // 1/sqrt(128)
#pragma unroll
    for (int i = 0; i < 4; ++i) {
#pragma unroll
      for (int r = 0; r < 4; ++r) {
        int row = mblk + wy * 64 + i * 16 + lg * 4 + r;   // bt
        int ti = row & (TLEN - 1), b = row >> 11;
#pragma unroll
        for (int jp = 0; jp < 2; ++jp) {
          float lo = acc[i][jp][r], hi = acc[i][jp + 2][r];
          int d = wx * 32 + jp * 16 + lm;                 // [0,64)
          int nl = nblk + d;                              // low-half global col
          if (nblk < 2048) {                              // q
            int qh = nl >> 7;
            float cs = costab[ti * 64 + d], sn = sintab[ti * 64 + d];
            float o0 = (lo * cs - hi * sn) * qscale;
            float o1 = (hi * cs + lo * sn) * qscale;
            size_t qo = (((size_t)(b * 16 + qh)) * TLEN + ti) * 128 + d;
            qbuf[qo] = (bf16_t)o0; qbuf[qo + 64] = (bf16_t)o1;
          } else if (nblk < 2560) {                       // k
            int hh = (nl - 2048) >> 7;
            float cs = costab[ti * 64 + d], sn = sintab[ti * 64 + d];
            float o0 = lo * cs - hi * sn;
            float o1 = hi * cs + lo * sn;
            size_t ko = (((size_t)(b * 4 + hh)) * TLEN + ti) * 128 + d;
            Kbuf[ko] = (bf16_t)o0; Kbuf[ko + 64] = (bf16_t)o1;
            size_t kvo = (size_t)row * 1024 + hh * 256 + d;
            kvout[kvo] = o0; kvout[kvo + 64] = o1;
          } else {                                        // v
            int hh = (nl - 2560) >> 7;
            size_t kvo = (size_t)row * 1024 + hh * 256 + 128 + d;
            kvout[kvo] = lo; kvout[kvo + 64] = hi;
          }
        }
      }
    }
  }
}

// ---------------------------------------------------------------------------
// V transpose: kv f32 [b][ti][h][128v @ +128] -> Vtb bf16 [b][h][d=128][tj=2048]
// ---------------------------------------------------------------------------
__global__ __launch_bounds__(256) void vtrans(const float* __restrict__ kvout,
                                              bf16_t* __restrict__ Vtb) {
  __shared__ bf16_t t[128][72];
  const int bx = blockIdx.x;          // (b*4+h)*32 + tt
  const int tt = bx & 31, bh = bx >> 5;
  const int b = bh >> 2, h = bh & 3;
  const int ti0 = tt * 64;
  const float* src = kvout + ((size_t)b * TLEN + ti0) * 1024 + h * 256 + 128;
  for (int idx = threadIdx.x; idx < 64 * 32; idx += 256) {
    int ti = idx >> 5, c4 = idx & 31;
    float4 v = *(const float4*)(src + (size_t)ti * 1024 + c4 * 4);
    t[c4 * 4 + 0][ti] = (bf16_t)v.x; t[c4 * 4 + 1][ti] = (bf16_t)v.y;
    t[c4 * 4 + 2][ti] = (bf16_t)v.z; t[c4 * 4 + 3][ti] = (bf16_t)v.w;
  }
  __syncthreads();
  bf16_t* dst = Vtb + (size_t)bh * 128 * TLEN + ti0;
  for (int idx = threadIdx.x; idx < 128 * 16; idx += 256) {
    int d = idx >> 4, ck = idx & 15;
    bf16x4 o = {t[d][ck * 4 + 0], t[d][ck * 4 + 1], t[d][ck * 4 + 2], t[d][ck * 4 + 3]};
    *(bf16x4*)(dst + (size_t)d * TLEN + ck * 4) = o;
  }
}

// ---------------------------------------------------------------------------
// Flash attention, bf16 MFMA. Block = (b, qh, 64-row q-tile), 4 waves,
// wave w owns rows [qt*64 + w*16, +16). 64-col K-tiles, no barriers in
// K-loop (wave-private LDS strip, stride 68, for P C->A relayout).
// Grid 1024 = 4 blocks/CU; qt <-> 31-qt pairing across bx +- 512 balances
// causal work per CU. Online softmax via 16-lane shfl_xor. Exact JAX dropout
// (raw-bits compare) on P after l-accumulation.
// ---------------------------------------------------------------------------
#define PSTR 68
__global__ __launch_bounds__(256, 4) void attn_flash(
    const bf16_t* __restrict__ qb, const bf16_t* __restrict__ Kb,
    const bf16_t* __restrict__ Vtb, bf16_t* __restrict__ midb) {
  __shared__ bf16_t P_lds[64 * PSTR];
  const int tid = threadIdx.x;
  const int w = tid >> 6, lane = tid & 63;
  const int lm = lane & 15, lg = lane >> 4;

  const int bx = blockIdx.x;
  const int bhalf = bx >> 9, idx = bx & 511;
  const int bqh = idx & 31, t4 = idx >> 5;          // t4 in 0..15
  const int qt = bhalf ? (31 - t4) : t4;            // 0..31
  const int qh = bqh & 15, b = bqh >> 4;
  const int h = qh & 3, g = qh >> 2;

  const bf16_t* qbase = qb + (((size_t)(b * 16 + qh)) * TLEN + qt * 64 + w * 16) * 128;
  const bf16_t* kbase = Kb + ((size_t)(b * 4 + h)) * TLEN * 128;
  const bf16_t* vbase = Vtb + ((size_t)(b * 4 + h)) * 128 * TLEN;

  // Q A-frags (16 rows); q already scaled by 1/sqrt(128)
  bf16x8 qf[4];
#pragma unroll
  for (int kk = 0; kk < 4; ++kk)
    qf[kk] = *(const bf16x8*)(qbase + (size_t)lm * 128 + kk * 32 + lg * 8);

  float mrow[4], lrow[4];
  f32x4 Oacc[8];
#pragma unroll
  for (int r = 0; r < 4; ++r) { mrow[r] = -3.0e38f; lrow[r] = 0.f; }
#pragma unroll
  for (int c = 0; c < 8; ++c) Oacc[c] = (f32x4)0.0f;

  const int row0 = qt * 64 + w * 16;           // wave's first q row
  const int nkt = qt + 1;                      // K-tiles needed
  const float L2E = 1.4426950408889634f;
  const uint32_t hdr = (uint32_t)((b * 4 + g) * 4 + h);
  bf16_t* Pw = P_lds + (w * 16) * PSTR;

  for (int kt = 0; kt < nkt; ++kt) {
    const int tj0 = kt * 64;
    // ---- S = Q K^T ----
    f32x4 S[4];
#pragma unroll
    for (int ct = 0; ct < 4; ++ct) S[ct] = (f32x4)0.0f;
#pragma unroll
    for (int ct = 0; ct < 4; ++ct) {
      bf16x8 kf[4];
#pragma unroll
      for (int kk = 0; kk < 4; ++kk)
        kf[kk] = *(const bf16x8*)(kbase + (size_t)(tj0 + ct * 16 + lm) * 128 + kk * 32 + lg * 8);
#pragma unroll
      for (int kk = 0; kk < 4; ++kk) S[ct] = mfma16(qf[kk], kf[kk], S[ct]);
    }

    // ---- causal mask (diagonal tile only) ----
    if (tj0 + 63 > row0) {
#pragma unroll
      for (int ct = 0; ct < 4; ++ct) {
        int tj = tj0 + ct * 16 + lm;
#pragma unroll
        for (int r = 0; r < 4; ++r) {
          int ti = row0 + lg * 4 + r;
          if (tj > ti) S[ct][r] = -1.0e30f;
        }
      }
    }

    // ---- online softmax ----
    float alpha[4];
    {
      float pm[4];
#pragma unroll
      for (int r = 0; r < 4; ++r)
        pm[r] = fmaxf(fmaxf(S[0][r], S[1][r]), fmaxf(S[2][r], S[3][r]));
#pragma unroll
      for (int off = 1; off < 16; off <<= 1)
#pragma unroll
        for (int r = 0; r < 4; ++r) pm[r] = fmaxf(pm[r], __shfl_xor(pm[r], off));
#pragma unroll
      for (int r = 0; r < 4; ++r) {
        float mn = fmaxf(mrow[r], pm[r]);
        alpha[r] = exp2f((mrow[r] - mn) * L2E);
        mrow[r] = mn;
      }
      float rs[4] = {0.f, 0.f, 0.f, 0.f};
#pragma unroll
      for (int ct = 0; ct < 4; ++ct)
#pragma unroll
        for (int r = 0; r < 4; ++r) {
          float p = exp2f((S[ct][r] - mrow[r]) * L2E);
          S[ct][r] = p;
          rs[r] += p;
        }
#pragma unroll
      for (int off = 1; off < 16; off <<= 1)
#pragma unroll
        for (int r = 0; r < 4; ++r) rs[r] += __shfl_xor(rs[r], off);
#pragma unroll
      for (int r = 0; r < 4; ++r) lrow[r] = lrow[r] * alpha[r] + rs[r];
    }

    // ---- dropout (raw-bits) + bf16 + LDS (C-layout -> A-layout) ----
#pragma unroll
    for (int r = 0; r < 4; ++r) {
      int ti = row0 + lg * 4 + r;
      uint32_t cb = (hdr << 22) + ((uint32_t)ti << 11) + (uint32_t)(tj0 + lm);
      int prow = (lg * 4 + r) * PSTR + lm;
#pragma unroll
      for (int ct = 0; ct < 4; ++ct) {
        uint32_t bits = threefry_bits(cb + (uint32_t)(ct * 16));
        float p = (bits < 0xE6666600u) ? S[ct][r] : 0.f;
        Pw[prow + ct * 16] = (bf16_t)p;
      }
    }
    asm volatile("s_waitcnt lgkmcnt(0)" ::: "memory");

    // ---- O = O*alpha + P V ----
#pragma unroll
    for (int c = 0; c < 8; ++c)
#pragma unroll
      for (int r = 0; r < 4; ++r) Oacc[c][r] *= alpha[r];

    bf16x8 aP[2];
#pragma unroll
    for (int kk = 0; kk < 2; ++kk)
      aP[kk] = *(const bf16x8*)&Pw[lm * PSTR + kk * 32 + lg * 8];
#pragma unroll
    for (int c = 0; c < 8; ++c) {
      bf16x8 vf[2];
#pragma unroll
      for (int kk = 0; kk < 2; ++kk)
        vf[kk] = *(const bf16x8*)(vbase + (size_t)(c * 16 + lm) * TLEN + tj0 + kk * 32 + lg * 8);
#pragma unroll
      for (int kk = 0; kk < 2; ++kk) Oacc[c] = mfma16(aP[kk], vf[kk], Oacc[c]);
    }
  }

  // ---- epilogue: normalize (1/l) * (1/0.9), write bf16 mid ----
  float invl[4];
#pragma unroll
  for (int r = 0; r < 4; ++r) invl[r] = (1.0f / 0.9f) / lrow[r];
#pragma unroll
  for (int c = 0; c < 8; ++c) {
    int d = c * 16 + lm;
#pragma unroll
    for (int r = 0; r < 4; ++r) {
      int bt = b * TLEN + row0 + lg * 4 + r;
      midb[(size_t)bt * DEMB + qh * 128 + d] = (bf16_t)(Oacc[c][r] * invl[r]);
    }
  }
}

// ---------------------------------------------------------------------------
extern "C" void kernel_launch(void* const* d_in, const int* in_sizes, int n_in,
                              void* d_out, int out_size, void* d_ws, size_t ws_size,
                              hipStream_t stream) {
  const float* x  = (const float*)d_in[0];
  const float* wq = (const float*)d_in[1];
  const float* wk = (const float*)d_in[2];
  const float* wv = (const float*)d_in[3];
  const float* wo = (const float*)d_in[4];
  float* out = (float*)d_out;
  float* kvc = out + ATTN_OUT_ELEMS;                    // [B,T,4,256] f32

  // workspace carve-up (~80.8 MB)
  char* ws = (char*)d_ws;
  bf16_t* Xb     = (bf16_t*)ws;                          ws += (size_t)4096 * 2048 * 2;  // 16.8MB
  bf16_t* Wqkvt  = (bf16_t*)ws;                          ws += (size_t)3072 * 2048 * 2;  // 12.6MB
  bf16_t* Wot    = (bf16_t*)ws;                          ws += (size_t)2048 * 2048 * 2;  // 8.4MB
  bf16_t* qbuf   = (bf16_t*)ws;                          ws += (size_t)2 * 16 * 2048 * 128 * 2; // 16.8MB
  bf16_t* Kbuf   = (bf16_t*)ws;                          ws += (size_t)2 * 4 * 2048 * 128 * 2;  // 4.2MB
  bf16_t* Vtb    = (bf16_t*)ws;                          ws += (size_t)2 * 4 * 128 * 2048 * 2;  // 4.2MB
  bf16_t* midb   = (bf16_t*)ws;                          ws += (size_t)4096 * 2048 * 2;  // 16.8MB
  float*  costab = (float*)ws;                           ws += (size_t)2048 * 64 * 4;    // 0.5MB
  float*  sintab = (float*)ws;                           // 0.5MB

  dim3 blk(256);
  rope_tab<<<512, blk, 0, stream>>>(costab, sintab);
  cvt_bf16<<<8192, blk, 0, stream>>>(x, Xb, 8388608 / 4);
  wtrans3<<<dim3(32, 48), blk, 0, stream>>>(wq, wk, wv, Wqkvt);
  wtrans1<<<dim3(32, 32), blk, 0, stream>>>(wo, Wot, 2048, 2048);

  gemm_bf16<1><<<dim3(32, 24), blk, 0, stream>>>(Xb, Wqkvt, nullptr, qbuf, Kbuf, kvc,
                                                 costab, sintab, 4096, 3072, 2048);
  vtrans<<<dim3(256), blk, 0, stream>>>(kvc, Vtb);
  attn_flash<<<dim3(1024), blk, 0, stream>>>(qbuf, Kbuf, Vtb, midb);
  gemm_bf16<0><<<dim3(32, 16), blk, 0, stream>>>(midb, Wot, out, nullptr, nullptr, nullptr,
                                                 nullptr, nullptr, 4096, 2048, 2048);
}